// Round 5
// baseline (923.908 us; speedup 1.0000x reference)
//
#include <hip/hip_runtime.h>
#include <hip/hip_bf16.h>
#include <math.h>

constexpr int DM = 1024;    // d_model
constexpr int NH = 16;      // heads
constexpr int DK = 64;      // head dim
constexpr int SQ = 2048;    // seq len
constexpr int BB = 2;       // batch
constexpr int MR = BB * SQ; // 4096 rows

typedef short bf16x8 __attribute__((ext_vector_type(8)));
typedef float f32x4 __attribute__((ext_vector_type(4)));

__device__ inline unsigned short f2bf(float f) {
  unsigned u = __float_as_uint(f);
  unsigned r = (u + 0x7fffu + ((u >> 16) & 1u)) >> 16;  // RNE
  return (unsigned short)r;
}
__device__ inline void unpack8(uint4 v, float* o) {
  o[0] = __uint_as_float(v.x << 16); o[1] = __uint_as_float(v.x & 0xffff0000u);
  o[2] = __uint_as_float(v.y << 16); o[3] = __uint_as_float(v.y & 0xffff0000u);
  o[4] = __uint_as_float(v.z << 16); o[5] = __uint_as_float(v.z & 0xffff0000u);
  o[6] = __uint_as_float(v.w << 16); o[7] = __uint_as_float(v.w & 0xffff0000u);
}

// -------- cast f32 -> bf16, 8 elems/thread --------
__global__ __launch_bounds__(256)
void cast_kernel(const float* __restrict__ in, unsigned short* __restrict__ out, int n8) {
  int i = blockIdx.x * 256 + threadIdx.x;
  if (i >= n8) return;
  float4 a = *(const float4*)&in[(size_t)i * 8];
  float4 b = *(const float4*)&in[(size_t)i * 8 + 4];
  ushort4 lo = {f2bf(a.x), f2bf(a.y), f2bf(a.z), f2bf(a.w)};
  ushort4 hi = {f2bf(b.x), f2bf(b.y), f2bf(b.z), f2bf(b.w)};
  *(ushort4*)&out[(size_t)i * 8] = lo;
  *(ushort4*)&out[(size_t)i * 8 + 4] = hi;
}

// -------- cast+transpose: W[K][N] f32 -> Wt[N][K] bf16 (32x32 tiles) --------
__global__ __launch_bounds__(256)
void transpose_cast_kernel(const float* __restrict__ W, unsigned short* __restrict__ Wt) {
  __shared__ float tl[32][33];
  const int tx = threadIdx.x & 31, ty = threadIdx.x >> 5;  // 32 x 8
  const int x0 = blockIdx.x * 32, y0 = blockIdx.y * 32;    // x0: n, y0: k
  #pragma unroll
  for (int i = 0; i < 4; ++i)
    tl[ty + i * 8][tx] = W[(size_t)(y0 + ty + i * 8) * DM + x0 + tx];
  __syncthreads();
  #pragma unroll
  for (int i = 0; i < 4; ++i)
    Wt[(size_t)(x0 + ty + i * 8) * DM + y0 + tx] = f2bf(tl[tx][ty + i * 8]);
}

// -------- bf16 MFMA GEMM: out = A[M,1024] * Wt[N,1024]^T + bias --------
// MODE 0: out f32 row-major [M,N].  MODE 1: out bf16 remapped [B,H,S,DK].
template<int MODE>
__global__ __launch_bounds__(256)
void mfma_gemm(const unsigned short* __restrict__ A, const unsigned short* __restrict__ Bt,
               const float* __restrict__ bias, void* __restrict__ outp)
{
  constexpr int K = DM, N = DM;
  constexpr int LDT = 72;                   // padded LDS row (144B = 9x16B): <=2-way banks
  __shared__ unsigned short As[128 * LDT];
  __shared__ unsigned short Bs[128 * LDT];
  const int t = threadIdx.x;
  const int w = t >> 6, ln = t & 63;
  const int wr = w >> 1, wc = w & 1;        // 2x2 wave grid, 64x64 per wave
  const int rb = blockIdx.y * 128, cb = blockIdx.x * 128;

  f32x4 acc[4][4] = {};

  for (int k0 = 0; k0 < K; k0 += 64) {
    // staging: tile is 128 rows x 64 bf16 = 1024 16B-granules; 4/thread/matrix
    uint4 ag[4], bg[4];
    #pragma unroll
    for (int i = 0; i < 4; ++i) {
      const int g = t + i * 256;
      const int r = g >> 3, c = (g & 7) * 8;
      ag[i] = *(const uint4*)&A[(size_t)(rb + r) * K + k0 + c];
      bg[i] = *(const uint4*)&Bt[(size_t)(cb + r) * K + k0 + c];
    }
    __syncthreads();  // protect previous iteration's LDS reads
    #pragma unroll
    for (int i = 0; i < 4; ++i) {
      const int g = t + i * 256;
      const int r = g >> 3, c = (g & 7) * 8;
      *(uint4*)&As[r * LDT + c] = ag[i];
      *(uint4*)&Bs[r * LDT + c] = bg[i];
    }
    __syncthreads();

    #pragma unroll
    for (int kk = 0; kk < 2; ++kk) {
      const int ko = kk * 32 + (ln >> 4) * 8;   // lane-group k offset
      const int rsel = ln & 15;
      bf16x8 af[4], bf[4];
      #pragma unroll
      for (int m = 0; m < 4; ++m)
        af[m] = *(const bf16x8*)&As[(wr * 64 + m * 16 + rsel) * LDT + ko];
      #pragma unroll
      for (int n = 0; n < 4; ++n)
        bf[n] = *(const bf16x8*)&Bs[(wc * 64 + n * 16 + rsel) * LDT + ko];
      #pragma unroll
      for (int m = 0; m < 4; ++m)
        #pragma unroll
        for (int n = 0; n < 4; ++n)
          acc[m][n] = __builtin_amdgcn_mfma_f32_16x16x32_bf16(af[m], bf[n], acc[m][n], 0, 0, 0);
    }
  }

  // epilogue: C/D layout col = ln&15, row = (ln>>4)*4 + i   [m89/m91 verified]
  const int cl = ln & 15, rg = (ln >> 4) * 4;
  #pragma unroll
  for (int m = 0; m < 4; ++m) {
    #pragma unroll
    for (int i = 0; i < 4; ++i) {
      const int r = rb + wr * 64 + m * 16 + rg + i;
      #pragma unroll
      for (int n = 0; n < 4; ++n) {
        const int c = cb + wc * 64 + n * 16 + cl;
        const float v = acc[m][n][i] + bias[c];
        if (MODE == 0) {
          ((float*)outp)[(size_t)r * N + c] = v;
        } else {
          const int b = r >> 11, s = r & 2047;  // r = b*2048 + s
          const int h = c >> 6, d = c & 63;     // c = h*64 + d
          ((unsigned short*)outp)[(((size_t)(b * NH + h)) * SQ + s) * DK + d] = f2bf(v);
        }
      }
    }
  }
}

// -------- Flash attention fp32 math, bf16 inputs/outputs --------
__global__ __launch_bounds__(256)
void attn_kernel(const unsigned short* __restrict__ Q, const unsigned short* __restrict__ Kp,
                 const unsigned short* __restrict__ V, unsigned short* __restrict__ ctx)
{
  __shared__ float Qs[64][68];
  __shared__ float Ks[64][68];
  __shared__ float Vs[64][64];
  const int t = threadIdx.x;
  const int bh = blockIdx.y;
  const int q0 = blockIdx.x * 64;
  const float scale = 0.125f;  // 1/sqrt(64)
  const unsigned short* Qb = Q  + (size_t)bh * SQ * DK;
  const unsigned short* Kb = Kp + (size_t)bh * SQ * DK;
  const unsigned short* Vb = V  + (size_t)bh * SQ * DK;

  // Q tile: 64 rows x 64 bf16 = 512 granules, 2/thread, scaled
  #pragma unroll
  for (int i = 0; i < 2; ++i) {
    int g = t + i * 256;
    int r = g >> 3, ds = (g & 7) * 8;
    uint4 v = *(const uint4*)&Qb[(size_t)(q0 + r) * DK + ds];
    float f[8]; unpack8(v, f);
    float4 lo = {f[0] * scale, f[1] * scale, f[2] * scale, f[3] * scale};
    float4 hi = {f[4] * scale, f[5] * scale, f[6] * scale, f[7] * scale};
    *(float4*)&Qs[r][ds] = lo;
    *(float4*)&Qs[r][ds + 4] = hi;
  }

  const int qi = t >> 2, lb = t & 3;
  float m = -1e30f, l = 0.f;
  float o[16] = {};

  for (int c0 = 0; c0 < SQ; c0 += 64) {
    uint4 kr[2], vr[2];
    #pragma unroll
    for (int i = 0; i < 2; ++i) {
      int g = t + i * 256;
      int r = g >> 3, ds = (g & 7) * 8;
      kr[i] = *(const uint4*)&Kb[(size_t)(c0 + r) * DK + ds];
      vr[i] = *(const uint4*)&Vb[(size_t)(c0 + r) * DK + ds];
    }
    __syncthreads();
    #pragma unroll
    for (int i = 0; i < 2; ++i) {
      int g = t + i * 256;
      int r = g >> 3, ds = (g & 7) * 8;
      float kf[8], vf[8];
      unpack8(kr[i], kf); unpack8(vr[i], vf);
      *(float4*)&Ks[r][ds]     = *(float4*)&kf[0];
      *(float4*)&Ks[r][ds + 4] = *(float4*)&kf[4];
      *(float4*)&Vs[r][ds]     = *(float4*)&vf[0];
      *(float4*)&Vs[r][ds + 4] = *(float4*)&vf[4];
    }
    __syncthreads();

    float sc[16];
    #pragma unroll
    for (int kk = 0; kk < 16; ++kk) sc[kk] = 0.f;
    #pragma unroll
    for (int d = 0; d < 64; d += 4) {
      float4 qv = *(const float4*)&Qs[qi][d];
      #pragma unroll
      for (int kk = 0; kk < 16; ++kk) {
        float4 kv = *(const float4*)&Ks[lb + kk * 4][d];
        sc[kk] = fmaf(qv.x, kv.x, sc[kk]);
        sc[kk] = fmaf(qv.y, kv.y, sc[kk]);
        sc[kk] = fmaf(qv.z, kv.z, sc[kk]);
        sc[kk] = fmaf(qv.w, kv.w, sc[kk]);
      }
    }

    float mloc = sc[0];
    #pragma unroll
    for (int kk = 1; kk < 16; ++kk) mloc = fmaxf(mloc, sc[kk]);
    mloc = fmaxf(mloc, __shfl_xor(mloc, 1, 4));
    mloc = fmaxf(mloc, __shfl_xor(mloc, 2, 4));
    const float mnew = fmaxf(m, mloc);
    const float corr = __expf(m - mnew);
    float psum = 0.f;
    #pragma unroll
    for (int kk = 0; kk < 16; ++kk) {
      sc[kk] = __expf(sc[kk] - mnew);
      psum += sc[kk];
    }
    psum += __shfl_xor(psum, 1, 4);
    psum += __shfl_xor(psum, 2, 4);
    l = l * corr + psum;
    m = mnew;
    #pragma unroll
    for (int j = 0; j < 16; ++j) o[j] *= corr;

    const int d0 = lb * 16;
    #pragma unroll
    for (int kk = 0; kk < 16; ++kk) {
      #pragma unroll
      for (int sl = 0; sl < 4; ++sl) {
        const float p = __shfl(sc[kk], sl, 4);
        const int k = kk * 4 + sl;
        float4 v0 = *(const float4*)&Vs[k][d0];
        float4 v1 = *(const float4*)&Vs[k][d0 + 4];
        float4 v2 = *(const float4*)&Vs[k][d0 + 8];
        float4 v3 = *(const float4*)&Vs[k][d0 + 12];
        o[0]  = fmaf(p, v0.x, o[0]);  o[1]  = fmaf(p, v0.y, o[1]);
        o[2]  = fmaf(p, v0.z, o[2]);  o[3]  = fmaf(p, v0.w, o[3]);
        o[4]  = fmaf(p, v1.x, o[4]);  o[5]  = fmaf(p, v1.y, o[5]);
        o[6]  = fmaf(p, v1.z, o[6]);  o[7]  = fmaf(p, v1.w, o[7]);
        o[8]  = fmaf(p, v2.x, o[8]);  o[9]  = fmaf(p, v2.y, o[9]);
        o[10] = fmaf(p, v2.z, o[10]); o[11] = fmaf(p, v2.w, o[11]);
        o[12] = fmaf(p, v3.x, o[12]); o[13] = fmaf(p, v3.y, o[13]);
        o[14] = fmaf(p, v3.z, o[14]); o[15] = fmaf(p, v3.w, o[15]);
      }
    }
  }

  const float inv = 1.f / l;
  const int b = bh >> 4, h = bh & 15;
  const int s = q0 + qi;
  unsigned short* dst = ctx + ((size_t)b * SQ + s) * DM + h * DK + lb * 16;
  unsigned pk[8];
  #pragma unroll
  for (int j = 0; j < 8; ++j)
    pk[j] = (unsigned)f2bf(o[2 * j] * inv) | ((unsigned)f2bf(o[2 * j + 1] * inv) << 16);
  uint4 w0 = {pk[0], pk[1], pk[2], pk[3]};
  uint4 w1 = {pk[4], pk[5], pk[6], pk[7]};
  *(uint4*)&dst[0] = w0;
  *(uint4*)&dst[8] = w1;
}

extern "C" void kernel_launch(void* const* d_in, const int* in_sizes, int n_in,
                              void* d_out, int out_size, void* d_ws, size_t ws_size,
                              hipStream_t stream) {
  const float* x  = (const float*)d_in[0];
  const float* Wq = (const float*)d_in[1];
  const float* bq = (const float*)d_in[2];
  const float* Wk = (const float*)d_in[3];
  const float* bk = (const float*)d_in[4];
  const float* Wv = (const float*)d_in[5];
  const float* bv = (const float*)d_in[6];
  const float* Wo = (const float*)d_in[7];
  const float* bo = (const float*)d_in[8];
  float* out = (float*)d_out;

  unsigned short* xb   = (unsigned short*)d_ws;            // [MR,DM] bf16, 8MB
  unsigned short* Wtq  = xb  + (size_t)MR * DM;            // [N,K] bf16, 2MB each
  unsigned short* Wtk  = Wtq + (size_t)DM * DM;
  unsigned short* Wtv  = Wtk + (size_t)DM * DM;
  unsigned short* Wto  = Wtv + (size_t)DM * DM;
  unsigned short* Qb   = Wto + (size_t)DM * DM;            // [B,H,S,DK] bf16, 8MB each
  unsigned short* Kb   = Qb  + (size_t)MR * DM;
  unsigned short* Vb   = Kb  + (size_t)MR * DM;
  unsigned short* ctxb = Vb  + (size_t)MR * DM;            // [B,S,DM] bf16, 8MB
  // total 48 MB

  cast_kernel<<<(MR * DM / 8 + 255) / 256, 256, 0, stream>>>(x, xb, MR * DM / 8);
  dim3 tg(DM / 32, DM / 32);
  transpose_cast_kernel<<<tg, 256, 0, stream>>>(Wq, Wtq);
  transpose_cast_kernel<<<tg, 256, 0, stream>>>(Wk, Wtk);
  transpose_cast_kernel<<<tg, 256, 0, stream>>>(Wv, Wtv);
  transpose_cast_kernel<<<tg, 256, 0, stream>>>(Wo, Wto);

  dim3 gg(DM / 128, MR / 128);  // (8, 32)
  mfma_gemm<1><<<gg, 256, 0, stream>>>(xb, Wtq, bq, Qb);
  mfma_gemm<1><<<gg, 256, 0, stream>>>(xb, Wtk, bk, Kb);
  mfma_gemm<1><<<gg, 256, 0, stream>>>(xb, Wtv, bv, Vb);

  attn_kernel<<<dim3(SQ / 64, BB * NH), 256, 0, stream>>>(Qb, Kb, Vb, ctxb);

  mfma_gemm<0><<<gg, 256, 0, stream>>>(ctxb, Wto, bo, out);
}

// Round 6
// 322.954 us; speedup vs baseline: 2.8608x; 2.8608x over previous
//
#include <hip/hip_runtime.h>
#include <hip/hip_bf16.h>
#include <math.h>

constexpr int DM = 1024;    // d_model
constexpr int NH = 16;      // heads
constexpr int DK = 64;      // head dim
constexpr int SQ = 2048;    // seq len
constexpr int BB = 2;       // batch
constexpr int MR = BB * SQ; // 4096 rows

typedef short bf16x8 __attribute__((ext_vector_type(8)));
typedef float f32x4 __attribute__((ext_vector_type(4)));

__device__ inline unsigned short f2bf(float f) {
  unsigned u = __float_as_uint(f);
  unsigned r = (u + 0x7fffu + ((u >> 16) & 1u)) >> 16;  // RNE
  return (unsigned short)r;
}
__device__ inline void unpack8(uint4 v, float* o) {
  o[0] = __uint_as_float(v.x << 16); o[1] = __uint_as_float(v.x & 0xffff0000u);
  o[2] = __uint_as_float(v.y << 16); o[3] = __uint_as_float(v.y & 0xffff0000u);
  o[4] = __uint_as_float(v.z << 16); o[5] = __uint_as_float(v.z & 0xffff0000u);
  o[6] = __uint_as_float(v.w << 16); o[7] = __uint_as_float(v.w & 0xffff0000u);
}

// XOR-swizzled element index for a [R][64] bf16 LDS tile.
// f(r) = (r&7) ^ ((r>>3)&7): fragment reads <=2-way; V^T b16 transpose
// writes exactly 2-way (the r>>3 term is required for that).
__device__ inline int swz(int r, int c) {
  int f = (r & 7) ^ ((r >> 3) & 7);
  return r * 64 + ((((c >> 3) ^ f) & 7) << 3) + (c & 7);
}

// -------- cast f32 -> bf16, 8 elems/thread --------
__global__ __launch_bounds__(256)
void cast_kernel(const float* __restrict__ in, unsigned short* __restrict__ out, int n8) {
  int i = blockIdx.x * 256 + threadIdx.x;
  if (i >= n8) return;
  float4 a = *(const float4*)&in[(size_t)i * 8];
  float4 b = *(const float4*)&in[(size_t)i * 8 + 4];
  ushort4 lo = {f2bf(a.x), f2bf(a.y), f2bf(a.z), f2bf(a.w)};
  ushort4 hi = {f2bf(b.x), f2bf(b.y), f2bf(b.z), f2bf(b.w)};
  *(ushort4*)&out[(size_t)i * 8] = lo;
  *(ushort4*)&out[(size_t)i * 8 + 4] = hi;
}

// -------- cast+transpose: W[K][N] f32 -> Wt[N][K] bf16 (32x32 tiles) --------
__global__ __launch_bounds__(256)
void transpose_cast_kernel(const float* __restrict__ W, unsigned short* __restrict__ Wt) {
  __shared__ float tl[32][33];
  const int tx = threadIdx.x & 31, ty = threadIdx.x >> 5;  // 32 x 8
  const int x0 = blockIdx.x * 32, y0 = blockIdx.y * 32;    // x0: n, y0: k
  #pragma unroll
  for (int i = 0; i < 4; ++i)
    tl[ty + i * 8][tx] = W[(size_t)(y0 + ty + i * 8) * DM + x0 + tx];
  __syncthreads();
  #pragma unroll
  for (int i = 0; i < 4; ++i)
    Wt[(size_t)(x0 + ty + i * 8) * DM + y0 + tx] = f2bf(tl[tx][ty + i * 8]);
}

// -------- bf16 MFMA GEMM: out = A[M,1024] * Wt[N,1024]^T + bias --------
// MODE 0: out f32 row-major [M,N].  MODE 1: out bf16 remapped [B,H,S,DK].
template<int MODE>
__global__ __launch_bounds__(256)
void mfma_gemm(const unsigned short* __restrict__ A, const unsigned short* __restrict__ Bt,
               const float* __restrict__ bias, void* __restrict__ outp)
{
  constexpr int K = DM, N = DM;
  constexpr int LDT = 72;                   // padded LDS row (144B): <=2-way banks
  __shared__ unsigned short As[128 * LDT];
  __shared__ unsigned short Bs[128 * LDT];
  const int t = threadIdx.x;
  const int w = t >> 6, ln = t & 63;
  const int wr = w >> 1, wc = w & 1;        // 2x2 wave grid, 64x64 per wave
  const int rb = blockIdx.y * 128, cb = blockIdx.x * 128;

  f32x4 acc[4][4] = {};

  for (int k0 = 0; k0 < K; k0 += 64) {
    // tile is 128 rows x 64 bf16 = 1024 16B-granules; 4/thread/matrix
    uint4 ag[4], bg[4];
    #pragma unroll
    for (int i = 0; i < 4; ++i) {
      const int g = t + i * 256;
      const int r = g >> 3, c = (g & 7) * 8;
      ag[i] = *(const uint4*)&A[(size_t)(rb + r) * K + k0 + c];
      bg[i] = *(const uint4*)&Bt[(size_t)(cb + r) * K + k0 + c];
    }
    __syncthreads();  // protect previous iteration's LDS reads
    #pragma unroll
    for (int i = 0; i < 4; ++i) {
      const int g = t + i * 256;
      const int r = g >> 3, c = (g & 7) * 8;
      *(uint4*)&As[r * LDT + c] = ag[i];
      *(uint4*)&Bs[r * LDT + c] = bg[i];
    }
    __syncthreads();

    #pragma unroll
    for (int kk = 0; kk < 2; ++kk) {
      const int ko = kk * 32 + (ln >> 4) * 8;   // lane-group k offset
      const int rsel = ln & 15;
      bf16x8 af[4], bf[4];
      #pragma unroll
      for (int m = 0; m < 4; ++m)
        af[m] = *(const bf16x8*)&As[(wr * 64 + m * 16 + rsel) * LDT + ko];
      #pragma unroll
      for (int n = 0; n < 4; ++n)
        bf[n] = *(const bf16x8*)&Bs[(wc * 64 + n * 16 + rsel) * LDT + ko];
      #pragma unroll
      for (int m = 0; m < 4; ++m)
        #pragma unroll
        for (int n = 0; n < 4; ++n)
          acc[m][n] = __builtin_amdgcn_mfma_f32_16x16x32_bf16(af[m], bf[n], acc[m][n], 0, 0, 0);
    }
  }

  // epilogue: C/D layout col = ln&15, row = (ln>>4)*4 + i
  const int cl = ln & 15, rg = (ln >> 4) * 4;
  #pragma unroll
  for (int m = 0; m < 4; ++m) {
    #pragma unroll
    for (int i = 0; i < 4; ++i) {
      const int r = rb + wr * 64 + m * 16 + rg + i;
      #pragma unroll
      for (int n = 0; n < 4; ++n) {
        const int c = cb + wc * 64 + n * 16 + cl;
        const float v = acc[m][n][i] + bias[c];
        if (MODE == 0) {
          ((float*)outp)[(size_t)r * N + c] = v;
        } else {
          const int b = r >> 11, s = r & 2047;  // r = b*2048 + s
          const int h = c >> 6, d = c & 63;     // c = h*64 + d
          ((unsigned short*)outp)[(((size_t)(b * NH + h)) * SQ + s) * DK + d] = f2bf(v);
        }
      }
    }
  }
}

// -------- MFMA flash attention --------
// Block = 4 waves, Q-tile 64 (16 rows/wave), KV-tile 64.
// Swapped QK^T (mfma(K,Q) -> S^T): lane ln holds S[q=ln&15][kk=16f+(ln>>4)*4+i].
// P round-trips LDS per wave; PV consumes stage-transposed V^T.
__global__ __launch_bounds__(256)
void attn_mfma(const unsigned short* __restrict__ Qp, const unsigned short* __restrict__ Kp,
               const unsigned short* __restrict__ Vp, unsigned short* __restrict__ ctx)
{
  __shared__ unsigned short Qs[64 * 64];
  __shared__ unsigned short Ks[64 * 64];
  __shared__ unsigned short Vt[64 * 64];      // V^T: [d][kv]
  __shared__ unsigned short Pl[4 * 16 * 64];  // per-wave P: [q][kk]
  const int t = threadIdx.x, w = t >> 6, ln = t & 63;
  const int bh = blockIdx.y, q0 = blockIdx.x * 64;
  const float scale = 0.125f;  // 1/sqrt(64), folded into exp args
  const unsigned short* Qb = Qp + (size_t)bh * SQ * DK;
  const unsigned short* Kb = Kp + (size_t)bh * SQ * DK;
  const unsigned short* Vb = Vp + (size_t)bh * SQ * DK;

  // stage Q tile (swizzled), then hoist this wave's B-fragments into regs
  #pragma unroll
  for (int i = 0; i < 2; ++i) {
    int g = t + i * 256, r = g >> 3, cg = g & 7;
    uint4 qv = *(const uint4*)&Qb[(size_t)(q0 + r) * DK + cg * 8];
    int f = (r & 7) ^ ((r >> 3) & 7);
    *(uint4*)&Qs[r * 64 + (((cg ^ f) & 7) << 3)] = qv;
  }
  __syncthreads();
  const int rsel = ln & 15, ko = (ln >> 4) * 8;
  bf16x8 qf[2];
  qf[0] = *(const bf16x8*)&Qs[swz(w * 16 + rsel, ko)];
  qf[1] = *(const bf16x8*)&Qs[swz(w * 16 + rsel, ko + 32)];

  f32x4 acc2[4] = {};          // O accum: O[q=(ln>>4)*4+i][d=16n+rsel]
  float m = -1e30f, l = 0.f;   // per-lane state for q-row = rsel

  // preload KV tile 0 into regs
  uint4 kg[2], vg[2];
  #pragma unroll
  for (int i = 0; i < 2; ++i) {
    int g = t + i * 256, r = g >> 3, cg = g & 7;
    kg[i] = *(const uint4*)&Kb[(size_t)r * DK + cg * 8];
    vg[i] = *(const uint4*)&Vb[(size_t)r * DK + cg * 8];
  }

  for (int c0 = 0; c0 < SQ; c0 += 64) {
    __syncthreads();  // previous tile's Ks/Vt reads done
    #pragma unroll
    for (int i = 0; i < 2; ++i) {
      int g = t + i * 256, r = g >> 3, cg = g & 7;
      int f = (r & 7) ^ ((r >> 3) & 7);
      *(uint4*)&Ks[r * 64 + (((cg ^ f) & 7) << 3)] = kg[i];
      const unsigned short* vv = (const unsigned short*)&vg[i];
      const int d0 = cg * 8;
      #pragma unroll
      for (int e = 0; e < 8; ++e)
        Vt[swz(d0 + e, r)] = vv[e];   // transpose write, 2-way banks
    }
    __syncthreads();

    // prefetch next KV tile (hides HBM latency under compute)
    if (c0 + 64 < SQ) {
      #pragma unroll
      for (int i = 0; i < 2; ++i) {
        int g = t + i * 256, r = g >> 3, cg = g & 7;
        kg[i] = *(const uint4*)&Kb[(size_t)(c0 + 64 + r) * DK + cg * 8];
        vg[i] = *(const uint4*)&Vb[(size_t)(c0 + 64 + r) * DK + cg * 8];
      }
    }

    // QK^T (swapped): s[fr] rows = kk window fr*16.., cols = wave's q window
    f32x4 s[4] = {};
    #pragma unroll
    for (int kw = 0; kw < 2; ++kw) {
      #pragma unroll
      for (int fr = 0; fr < 4; ++fr) {
        bf16x8 kf = *(const bf16x8*)&Ks[swz(fr * 16 + rsel, ko + 32 * kw)];
        s[fr] = __builtin_amdgcn_mfma_f32_16x16x32_bf16(kf, qf[kw], s[fr], 0, 0, 0);
      }
    }

    // online softmax for q-row = rsel (16 scores in-lane, 4 replicas)
    float tm = s[0][0];
    #pragma unroll
    for (int fr = 0; fr < 4; ++fr)
      #pragma unroll
      for (int i = 0; i < 4; ++i) tm = fmaxf(tm, s[fr][i]);
    tm = fmaxf(tm, __shfl_xor(tm, 16));
    tm = fmaxf(tm, __shfl_xor(tm, 32));
    const float mnew = fmaxf(m, tm);
    const float corr = __expf((m - mnew) * scale);
    float p[4][4], ps = 0.f;
    #pragma unroll
    for (int fr = 0; fr < 4; ++fr)
      #pragma unroll
      for (int i = 0; i < 4; ++i) {
        p[fr][i] = __expf((s[fr][i] - mnew) * scale);
        ps += p[fr][i];
      }
    ps += __shfl_xor(ps, 16);
    ps += __shfl_xor(ps, 32);
    l = l * corr + ps;
    m = mnew;

    // write P (bf16) to this wave's LDS region: Pl[q=rsel][kk0..kk0+3]
    #pragma unroll
    for (int fr = 0; fr < 4; ++fr) {
      unsigned lo = (unsigned)f2bf(p[fr][0]) | ((unsigned)f2bf(p[fr][1]) << 16);
      unsigned hi = (unsigned)f2bf(p[fr][2]) | ((unsigned)f2bf(p[fr][3]) << 16);
      uint2 pv = {lo, hi};
      const int kk0 = (ln >> 4) * 4 + fr * 16;
      *(uint2*)&Pl[w * 1024 + swz(rsel, kk0)] = pv;
    }

    // rescale O: corr for q_out=(ln>>4)*4+i lives at lane q_out
    float ci[4];
    #pragma unroll
    for (int i = 0; i < 4; ++i) ci[i] = __shfl(corr, (ln >> 4) * 4 + i);
    #pragma unroll
    for (int n = 0; n < 4; ++n)
      #pragma unroll
      for (int i = 0; i < 4; ++i) acc2[n][i] *= ci[i];

    // PV: A = P rows (wave-local), B = Vt rows
    #pragma unroll
    for (int kw = 0; kw < 2; ++kw) {
      bf16x8 pf = *(const bf16x8*)&Pl[w * 1024 + swz(rsel, ko + 32 * kw)];
      #pragma unroll
      for (int n = 0; n < 4; ++n) {
        bf16x8 vf = *(const bf16x8*)&Vt[swz(n * 16 + rsel, ko + 32 * kw)];
        acc2[n] = __builtin_amdgcn_mfma_f32_16x16x32_bf16(pf, vf, acc2[n], 0, 0, 0);
      }
    }
  }

  // epilogue: divide by l (per output row) and store bf16 ctx [B][S][DM]
  const float rl = 1.0f / l;
  float ri[4];
  #pragma unroll
  for (int i = 0; i < 4; ++i) ri[i] = __shfl(rl, (ln >> 4) * 4 + i);
  const int b = bh >> 4, h = bh & 15;
  #pragma unroll
  for (int n = 0; n < 4; ++n)
    #pragma unroll
    for (int i = 0; i < 4; ++i) {
      const int srow = q0 + w * 16 + (ln >> 4) * 4 + i;
      ctx[((size_t)(b * SQ + srow)) * DM + h * 64 + n * 16 + rsel] =
          f2bf(acc2[n][i] * ri[i]);
    }
}

extern "C" void kernel_launch(void* const* d_in, const int* in_sizes, int n_in,
                              void* d_out, int out_size, void* d_ws, size_t ws_size,
                              hipStream_t stream) {
  const float* x  = (const float*)d_in[0];
  const float* Wq = (const float*)d_in[1];
  const float* bq = (const float*)d_in[2];
  const float* Wk = (const float*)d_in[3];
  const float* bk = (const float*)d_in[4];
  const float* Wv = (const float*)d_in[5];
  const float* bv = (const float*)d_in[6];
  const float* Wo = (const float*)d_in[7];
  const float* bo = (const float*)d_in[8];
  float* out = (float*)d_out;

  unsigned short* xb   = (unsigned short*)d_ws;            // [MR,DM] bf16, 8MB
  unsigned short* Wtq  = xb  + (size_t)MR * DM;            // [N,K] bf16, 2MB each
  unsigned short* Wtk  = Wtq + (size_t)DM * DM;
  unsigned short* Wtv  = Wtk + (size_t)DM * DM;
  unsigned short* Wto  = Wtv + (size_t)DM * DM;
  unsigned short* Qb   = Wto + (size_t)DM * DM;            // [B,H,S,DK] bf16, 8MB each
  unsigned short* Kb   = Qb  + (size_t)MR * DM;
  unsigned short* Vb   = Kb  + (size_t)MR * DM;
  unsigned short* ctxb = Vb  + (size_t)MR * DM;            // [B,S,DM] bf16, 8MB
  // total 48 MB

  cast_kernel<<<(MR * DM / 8 + 255) / 256, 256, 0, stream>>>(x, xb, MR * DM / 8);
  dim3 tg(DM / 32, DM / 32);
  transpose_cast_kernel<<<tg, 256, 0, stream>>>(Wq, Wtq);
  transpose_cast_kernel<<<tg, 256, 0, stream>>>(Wk, Wtk);
  transpose_cast_kernel<<<tg, 256, 0, stream>>>(Wv, Wtv);
  transpose_cast_kernel<<<tg, 256, 0, stream>>>(Wo, Wto);

  dim3 gg(DM / 128, MR / 128);  // (8, 32)
  mfma_gemm<1><<<gg, 256, 0, stream>>>(xb, Wtq, bq, Qb);
  mfma_gemm<1><<<gg, 256, 0, stream>>>(xb, Wtk, bk, Kb);
  mfma_gemm<1><<<gg, 256, 0, stream>>>(xb, Wtv, bv, Vb);

  attn_mfma<<<dim3(SQ / 64, BB * NH), 256, 0, stream>>>(Qb, Kb, Vb, ctxb);

  mfma_gemm<0><<<gg, 256, 0, stream>>>(ctxb, Wto, bo, out);
}